// Round 1
// baseline (214.558 us; speedup 1.0000x reference)
//
#include <hip/hip_runtime.h>
#include <hip/hip_bf16.h>

#define NI 768
#define NJ 768
#define CN 512
#define CP 128
#define NH 8
#define CH 32
#define HC 256   // NH*CH

typedef float  fx4  __attribute__((ext_vector_type(4)));
typedef float  fx2  __attribute__((ext_vector_type(2)));
typedef short  bv8  __attribute__((ext_vector_type(8)));

__device__ __forceinline__ short f2bf(float f) {
    __hip_bfloat16 h = __float2bfloat16(f);
    return *reinterpret_cast<short*>(&h);
}
__device__ __forceinline__ float bf2f(unsigned short u) {
    union { unsigned int u; float f; } c; c.u = ((unsigned int)u) << 16; return c.f;
}

// ---------------------------------------------------------------- prep
// wcat[c][o] (bf16): o<8 -> ln_p_w[c]*W_pb[c][o]; o>=8 -> ln_p_w[c]*W_pg[c][o-8]
// scal[o]    = sum_c wcat[c][o]  (f32, from the bf16-rounded values)
// scal[16+o] = sum_c ln_p_b[c]*W[c][o] + bproj[o]
__global__ __launch_bounds__(256) void prep_kernel(
    const float* __restrict__ lnpw, const float* __restrict__ lnpb,
    const float* __restrict__ Wpb, const float* __restrict__ bpb,
    const float* __restrict__ Wpg, const float* __restrict__ bpg,
    unsigned short* __restrict__ wcat, float* __restrict__ scal)
{
    const int t = threadIdx.x;
    for (int idx = t; idx < CP * 16; idx += 256) {
        int c = idx >> 4, o = idx & 15;
        float w = (o < 8) ? Wpb[c * 8 + o] : Wpg[c * 8 + (o - 8)];
        wcat[idx] = (unsigned short)(unsigned short)f2bf(lnpw[c] * w);
    }
    __syncthreads();
    if (t < 16) {
        float s = 0.f, cacc = 0.f;
        for (int c = 0; c < CP; ++c) {
            s += bf2f(wcat[c * 16 + t]);
            float w = (t < 8) ? Wpb[c * 8 + t] : Wpg[c * 8 + (t - 8)];
            cacc += lnpb[c] * w;
        }
        scal[t] = s;
        scal[16 + t] = cacc + ((t < 8) ? bpb[t] : bpg[t - 8]);
    }
}

// ---------------------------------------------------------------- node LN
// blockIdx < NI: qx row from node_i; else kx row from node_j
__global__ __launch_bounds__(256) void ln_node_kernel(
    const float* __restrict__ xi, const float* __restrict__ xj,
    const float* __restrict__ wi, const float* __restrict__ bi,
    const float* __restrict__ wj, const float* __restrict__ bj,
    float* __restrict__ qx, float* __restrict__ kx)
{
    const bool isj = (blockIdx.x >= NI);
    const int row = isj ? blockIdx.x - NI : blockIdx.x;
    const float* x = (isj ? xj : xi) + (size_t)row * CN;
    const float* w = isj ? wj : wi;
    const float* b = isj ? bj : bi;
    float* outp = (isj ? kx : qx) + (size_t)row * CN;
    const int t = threadIdx.x;

    fx2 v = *(const fx2*)(x + t * 2);
    float s = v[0] + v[1];
    float q = v[0] * v[0] + v[1] * v[1];
#pragma unroll
    for (int d = 1; d < 64; d <<= 1) { s += __shfl_xor(s, d); q += __shfl_xor(q, d); }
    __shared__ float ls[4], lq[4];
    if ((t & 63) == 0) { ls[t >> 6] = s; lq[t >> 6] = q; }
    __syncthreads();
    s = ls[0] + ls[1] + ls[2] + ls[3];
    q = lq[0] + lq[1] + lq[2] + lq[3];
    float mean = s * (1.f / CN);
    float var = q * (1.f / CN) - mean * mean;
    float rs = rsqrtf(var + 1e-5f);
    fx2 o;
    o[0] = (v[0] - mean) * rs * w[t * 2] + b[t * 2];
    o[1] = (v[1] - mean) * rs * w[t * 2 + 1] + b[t * 2 + 1];
    *(fx2*)(outp + t * 2) = o;
}

// ---------------------------------------------------------------- q/k/v/g projections
// grid (NI/8, 4); thread = output col; 8 rows per block for weight reuse
__global__ __launch_bounds__(256) void proj_kernel(
    const float* __restrict__ qx, const float* __restrict__ kx,
    const float* __restrict__ Wq, const float* __restrict__ Wk,
    const float* __restrict__ Wv, const float* __restrict__ Wg,
    const float* __restrict__ bg,
    float* __restrict__ qs, float* __restrict__ ks,
    float* __restrict__ vs, float* __restrict__ gs)
{
    const int mat = blockIdx.y;
    const int r0 = blockIdx.x * 8;
    const float* x = (mat == 1 || mat == 2) ? kx : qx;
    const float* W = (mat == 0) ? Wq : (mat == 1) ? Wk : (mat == 2) ? Wv : Wg;
    float* outp    = (mat == 0) ? qs : (mat == 1) ? ks : (mat == 2) ? vs : gs;
    const int col = threadIdx.x;

    float acc[8] = {0.f,0.f,0.f,0.f,0.f,0.f,0.f,0.f};
    for (int cc = 0; cc < CN; cc += 4) {
        float w0 = W[(size_t)(cc + 0) * HC + col];
        float w1 = W[(size_t)(cc + 1) * HC + col];
        float w2 = W[(size_t)(cc + 2) * HC + col];
        float w3 = W[(size_t)(cc + 3) * HC + col];
#pragma unroll
        for (int r = 0; r < 8; ++r) {
            fx4 xv = *(const fx4*)(x + (size_t)(r0 + r) * CN + cc);
            acc[r] = fmaf(xv[0], w0, acc[r]);
            acc[r] = fmaf(xv[1], w1, acc[r]);
            acc[r] = fmaf(xv[2], w2, acc[r]);
            acc[r] = fmaf(xv[3], w3, acc[r]);
        }
    }
#pragma unroll
    for (int r = 0; r < 8; ++r) {
        float v = acc[r];
        if (mat == 0) v *= 0.17677669529663687f;   // C_HID^-0.5
        if (mat == 3) v = 1.f / (1.f + __expf(-(v + bg[col])));
        outp[(size_t)(r0 + r) * HC + col] = v;
    }
}

// ---------------------------------------------------------------- pair bias (the big one)
// One wave = 16 pairs (one i, 16 consecutive j). LN folded into projection:
//   out_o = rs*(dot_o - m*spb_o) + cpb_o,  dot via MFMA 16x16x32 bf16, K=128.
// bias[i][j][h] = pb*sigmoid(pg) + (mask-1)*1e9
__global__ __launch_bounds__(256) void pair_bias_kernel(
    const float* __restrict__ pair, const float* __restrict__ pmask,
    const unsigned short* __restrict__ wcat, const float* __restrict__ scal,
    float* __restrict__ bias)
{
    const int lane = threadIdx.x & 63;
    const int wave = threadIdx.x >> 6;
    const int tile = blockIdx.x * 4 + wave;
    const int i  = tile / (NJ / 16);
    const int jt = (tile % (NJ / 16)) * 16;
    const int o  = lane & 15;   // B col (output) and A row (pair)
    const int kq = lane >> 4;   // k-quad

    // B fragments from constant wcat: wcat[s*32 + kq*8 + j][o]
    bv8 bfrag[4];
#pragma unroll
    for (int s = 0; s < 4; ++s)
#pragma unroll
        for (int j = 0; j < 8; ++j)
            bfrag[s][j] = (short)wcat[(s * 32 + kq * 8 + j) * 16 + o];

    const float spb = scal[o];
    const float cpb = scal[16 + o];

    // A: pair row (jt+o), channels kq*8 + s*32 + [0..7]
    const float* prow = pair + ((size_t)i * NJ + (jt + o)) * CP + kq * 8;
    fx4 x0[4], x1[4];
#pragma unroll
    for (int s = 0; s < 4; ++s) {
        x0[s] = *(const fx4*)(prow + s * 32);
        x1[s] = *(const fx4*)(prow + s * 32 + 4);
    }
    float sum = 0.f, ssq = 0.f;
    bv8 afrag[4];
#pragma unroll
    for (int s = 0; s < 4; ++s) {
#pragma unroll
        for (int u = 0; u < 4; ++u) {
            float a = x0[s][u], b = x1[s][u];
            sum += a + b;
            ssq = fmaf(a, a, ssq);
            ssq = fmaf(b, b, ssq);
            afrag[s][u]     = f2bf(a);
            afrag[s][u + 4] = f2bf(b);
        }
    }
    // stats butterfly: lanes {l, l^16, l^32, l^48} hold pair (l&15)
    sum += __shfl_xor(sum, 16); ssq += __shfl_xor(ssq, 16);
    sum += __shfl_xor(sum, 32); ssq += __shfl_xor(ssq, 32);

    fx4 acc = {0.f, 0.f, 0.f, 0.f};
#pragma unroll
    for (int s = 0; s < 4; ++s)
        acc = __builtin_amdgcn_mfma_f32_16x16x32_bf16(afrag[s], bfrag[s], acc, 0, 0, 0);

    // D: lane holds rows kq*4+r, col o
#pragma unroll
    for (int r = 0; r < 4; ++r) {
        const int p = kq * 4 + r;
        float sp = __shfl(sum, p);
        float qp = __shfl(ssq, p);
        float mean = sp * (1.f / CP);
        float var  = qp * (1.f / CP) - mean * mean;
        float rstd = rsqrtf(var + 1e-5f);
        float pre  = rstd * (acc[r] - mean * spb) + cpb;
        float part = __shfl_xor(pre, 8);   // pb<->pg partner
        if (o < 8) {
            float sig = 1.f / (1.f + __expf(-part));
            int j = jt + p;
            float b = pre * sig + (pmask[(size_t)i * NJ + j] - 1.f) * 1.0e9f;
            bias[((size_t)i * NJ + j) * NH + o] = b;
        }
    }
}

// ---------------------------------------------------------------- attention (2 query rows / block)
__global__ __launch_bounds__(256) void attn_kernel(
    const float* __restrict__ qs, const float* __restrict__ ks,
    const float* __restrict__ vs, const float* __restrict__ bias,
    const float* __restrict__ gs, float* __restrict__ og)
{
    __shared__ float sc[2][NH][NJ];   // scores -> probs, 48 KB
    const int i0 = blockIdx.x * 2;
    const int t = threadIdx.x;
    const int h = t >> 5;
    const int jl = t & 31;

    fx4 q0[8], q1[8];
#pragma unroll
    for (int u = 0; u < 8; ++u) {
        q0[u] = *(const fx4*)(qs + (size_t)i0 * HC + h * CH + u * 4);
        q1[u] = *(const fx4*)(qs + (size_t)(i0 + 1) * HC + h * CH + u * 4);
    }
    for (int jj = 0; jj < NJ / 32; ++jj) {
        const int j = jl + jj * 32;
        const float* kp = ks + (size_t)j * HC + h * CH;
        float s0 = 0.f, s1 = 0.f;
#pragma unroll
        for (int u = 0; u < 8; ++u) {
            fx4 kv = *(const fx4*)(kp + u * 4);
            s0 += q0[u][0]*kv[0] + q0[u][1]*kv[1] + q0[u][2]*kv[2] + q0[u][3]*kv[3];
            s1 += q1[u][0]*kv[0] + q1[u][1]*kv[1] + q1[u][2]*kv[2] + q1[u][3]*kv[3];
        }
        sc[0][h][j] = s0 + bias[((size_t)i0 * NJ + j) * NH + h];
        sc[1][h][j] = s1 + bias[((size_t)(i0 + 1) * NJ + j) * NH + h];
    }
    __syncthreads();

    float m0 = -1.0e30f, m1 = -1.0e30f;
    for (int jj = 0; jj < NJ / 32; ++jj) {
        int j = jl + jj * 32;
        m0 = fmaxf(m0, sc[0][h][j]);
        m1 = fmaxf(m1, sc[1][h][j]);
    }
#pragma unroll
    for (int d = 1; d < 32; d <<= 1) {
        m0 = fmaxf(m0, __shfl_xor(m0, d));
        m1 = fmaxf(m1, __shfl_xor(m1, d));
    }
    float s0 = 0.f, s1 = 0.f;
    for (int jj = 0; jj < NJ / 32; ++jj) {
        int j = jl + jj * 32;
        float p0 = __expf(sc[0][h][j] - m0);
        float p1 = __expf(sc[1][h][j] - m1);
        sc[0][h][j] = p0; sc[1][h][j] = p1;
        s0 += p0; s1 += p1;
    }
#pragma unroll
    for (int d = 1; d < 32; d <<= 1) { s0 += __shfl_xor(s0, d); s1 += __shfl_xor(s1, d); }
    const float inv0 = 1.f / s0, inv1 = 1.f / s1;
    __syncthreads();

    const int c = t & 31;
    float o0 = 0.f, o1 = 0.f;
    for (int j = 0; j < NJ; j += 4) {
        fx4 p0 = *(const fx4*)&sc[0][h][j];
        fx4 p1 = *(const fx4*)&sc[1][h][j];
#pragma unroll
        for (int u = 0; u < 4; ++u) {
            float vv = vs[(size_t)(j + u) * HC + h * CH + c];
            o0 = fmaf(p0[u], vv, o0);
            o1 = fmaf(p1[u], vv, o1);
        }
    }
    o0 *= inv0; o1 *= inv1;
    const size_t b0 = (size_t)i0 * HC + h * CH + c;
    const size_t b1 = (size_t)(i0 + 1) * HC + h * CH + c;
    og[b0] = o0 * gs[b0];
    og[b1] = o1 * gs[b1];
}

// ---------------------------------------------------------------- output projection + residual
__global__ __launch_bounds__(256) void out_proj_kernel(
    const float* __restrict__ og, const float* __restrict__ qx,
    const float* __restrict__ Wo, const float* __restrict__ bo,
    const float* __restrict__ mi, float* __restrict__ outp)
{
    const int r0 = blockIdx.x * 4;
    const int t = threadIdx.x;
    float acc[4][2] = {{0,0},{0,0},{0,0},{0,0}};
    for (int cc = 0; cc < HC; cc += 4) {
        fx4 xr0 = *(const fx4*)(og + (size_t)(r0 + 0) * HC + cc);
        fx4 xr1 = *(const fx4*)(og + (size_t)(r0 + 1) * HC + cc);
        fx4 xr2 = *(const fx4*)(og + (size_t)(r0 + 2) * HC + cc);
        fx4 xr3 = *(const fx4*)(og + (size_t)(r0 + 3) * HC + cc);
#pragma unroll
        for (int u = 0; u < 4; ++u) {
            float w0 = Wo[(size_t)(cc + u) * CN + t];
            float w1 = Wo[(size_t)(cc + u) * CN + 256 + t];
            acc[0][0] = fmaf(xr0[u], w0, acc[0][0]); acc[0][1] = fmaf(xr0[u], w1, acc[0][1]);
            acc[1][0] = fmaf(xr1[u], w0, acc[1][0]); acc[1][1] = fmaf(xr1[u], w1, acc[1][1]);
            acc[2][0] = fmaf(xr2[u], w0, acc[2][0]); acc[2][1] = fmaf(xr2[u], w1, acc[2][1]);
            acc[3][0] = fmaf(xr3[u], w0, acc[3][0]); acc[3][1] = fmaf(xr3[u], w1, acc[3][1]);
        }
    }
#pragma unroll
    for (int r = 0; r < 4; ++r) {
        float mk = mi[r0 + r];
        size_t base = (size_t)(r0 + r) * CN;
        outp[base + t]       = qx[base + t]       + (acc[r][0] + bo[t])       * mk;
        outp[base + 256 + t] = qx[base + 256 + t] + (acc[r][1] + bo[t + 256]) * mk;
    }
}

// ---------------------------------------------------------------- launch
extern "C" void kernel_launch(void* const* d_in, const int* in_sizes, int n_in,
                              void* d_out, int out_size, void* d_ws, size_t ws_size,
                              hipStream_t stream)
{
    const float* node_i = (const float*)d_in[0];
    const float* node_j = (const float*)d_in[1];
    const float* pair   = (const float*)d_in[2];
    const float* pmask  = (const float*)d_in[3];
    const float* nmask  = (const float*)d_in[4];
    const float* ln_i_w = (const float*)d_in[5];
    const float* ln_i_b = (const float*)d_in[6];
    const float* ln_j_w = (const float*)d_in[7];
    const float* ln_j_b = (const float*)d_in[8];
    const float* ln_p_w = (const float*)d_in[9];
    const float* ln_p_b = (const float*)d_in[10];
    const float* W_pb   = (const float*)d_in[11];
    const float* b_pb   = (const float*)d_in[12];
    const float* W_pg   = (const float*)d_in[13];
    const float* b_pg   = (const float*)d_in[14];
    const float* Wq     = (const float*)d_in[15];
    const float* Wk     = (const float*)d_in[16];
    const float* Wv     = (const float*)d_in[17];
    const float* Wg     = (const float*)d_in[18];
    const float* bg     = (const float*)d_in[19];
    const float* Wo     = (const float*)d_in[20];
    const float* bo     = (const float*)d_in[21];
    float* outp = (float*)d_out;

    float* w  = (float*)d_ws;
    float* qx = w;                       // [NI][CN]
    float* kx = qx + (size_t)NI * CN;    // [NJ][CN]
    float* qs = kx + (size_t)NJ * CN;    // [NI][HC]
    float* ks = qs + (size_t)NI * HC;    // [NJ][HC]
    float* vs = ks + (size_t)NJ * HC;    // [NJ][HC]
    float* gs = vs + (size_t)NJ * HC;    // [NI][HC]
    float* og = gs + (size_t)NI * HC;    // [NI][HC]
    float* bias = og + (size_t)NI * HC;  // [NI][NJ][NH]
    unsigned short* wcat = (unsigned short*)(bias + (size_t)NI * NJ * NH); // [CP][16] bf16
    float* scal = (float*)(wcat + CP * 16);  // spb[16] | cpb[16]

    hipLaunchKernelGGL(prep_kernel, dim3(1), dim3(256), 0, stream,
                       ln_p_w, ln_p_b, W_pb, b_pb, W_pg, b_pg, wcat, scal);
    hipLaunchKernelGGL(ln_node_kernel, dim3(2 * NI), dim3(256), 0, stream,
                       node_i, node_j, ln_i_w, ln_i_b, ln_j_w, ln_j_b, qx, kx);
    hipLaunchKernelGGL(proj_kernel, dim3(NI / 8, 4), dim3(256), 0, stream,
                       qx, kx, Wq, Wk, Wv, Wg, bg, qs, ks, vs, gs);
    hipLaunchKernelGGL(pair_bias_kernel, dim3((NI * NJ) / 64), dim3(256), 0, stream,
                       pair, pmask, wcat, scal, bias);
    hipLaunchKernelGGL(attn_kernel, dim3(NI / 2), dim3(256), 0, stream,
                       qs, ks, vs, bias, gs, og);
    hipLaunchKernelGGL(out_proj_kernel, dim3(NI / 4), dim3(256), 0, stream,
                       og, qx, Wo, bo, nmask, outp);
}

// Round 2
// 170.310 us; speedup vs baseline: 1.2598x; 1.2598x over previous
//
#include <hip/hip_runtime.h>
#include <hip/hip_bf16.h>

#define NI 768
#define NJ 768
#define CN 512
#define CP 128
#define NH 8
#define CH 32
#define HC 256   // NH*CH

typedef float  fx4  __attribute__((ext_vector_type(4)));
typedef float  fx2  __attribute__((ext_vector_type(2)));
typedef short  bv8  __attribute__((ext_vector_type(8)));

__device__ __forceinline__ short f2bf(float f) {
    __hip_bfloat16 h = __float2bfloat16(f);
    return *reinterpret_cast<short*>(&h);
}
__device__ __forceinline__ float bf2f(unsigned short u) {
    union { unsigned int u; float f; } c; c.u = ((unsigned int)u) << 16; return c.f;
}

// ---------------------------------------------------------------- prep
__global__ __launch_bounds__(256) void prep_kernel(
    const float* __restrict__ lnpw, const float* __restrict__ lnpb,
    const float* __restrict__ Wpb, const float* __restrict__ bpb,
    const float* __restrict__ Wpg, const float* __restrict__ bpg,
    unsigned short* __restrict__ wcat, float* __restrict__ scal)
{
    const int t = threadIdx.x;
    for (int idx = t; idx < CP * 16; idx += 256) {
        int c = idx >> 4, o = idx & 15;
        float w = (o < 8) ? Wpb[c * 8 + o] : Wpg[c * 8 + (o - 8)];
        wcat[idx] = (unsigned short)f2bf(lnpw[c] * w);
    }
    __syncthreads();
    if (t < 16) {
        float s = 0.f, cacc = 0.f;
        for (int c = 0; c < CP; ++c) {
            s += bf2f(wcat[c * 16 + t]);
            float w = (t < 8) ? Wpb[c * 8 + t] : Wpg[c * 8 + (t - 8)];
            cacc += lnpb[c] * w;
        }
        scal[t] = s;
        scal[16 + t] = cacc + ((t < 8) ? bpb[t] : bpg[t - 8]);
    }
}

// ---------------------------------------------------------------- node LN
__global__ __launch_bounds__(256) void ln_node_kernel(
    const float* __restrict__ xi, const float* __restrict__ xj,
    const float* __restrict__ wi, const float* __restrict__ bi,
    const float* __restrict__ wj, const float* __restrict__ bj,
    float* __restrict__ qx, float* __restrict__ kx)
{
    const bool isj = (blockIdx.x >= NI);
    const int row = isj ? blockIdx.x - NI : blockIdx.x;
    const float* x = (isj ? xj : xi) + (size_t)row * CN;
    const float* w = isj ? wj : wi;
    const float* b = isj ? bj : bi;
    float* outp = (isj ? kx : qx) + (size_t)row * CN;
    const int t = threadIdx.x;

    fx2 v = *(const fx2*)(x + t * 2);
    float s = v[0] + v[1];
    float q = v[0] * v[0] + v[1] * v[1];
#pragma unroll
    for (int d = 1; d < 64; d <<= 1) { s += __shfl_xor(s, d); q += __shfl_xor(q, d); }
    __shared__ float ls[4], lq[4];
    if ((t & 63) == 0) { ls[t >> 6] = s; lq[t >> 6] = q; }
    __syncthreads();
    s = ls[0] + ls[1] + ls[2] + ls[3];
    q = lq[0] + lq[1] + lq[2] + lq[3];
    float mean = s * (1.f / CN);
    float var = q * (1.f / CN) - mean * mean;
    float rs = rsqrtf(var + 1e-5f);
    fx2 o;
    o[0] = (v[0] - mean) * rs * w[t * 2] + b[t * 2];
    o[1] = (v[1] - mean) * rs * w[t * 2 + 1] + b[t * 2 + 1];
    *(fx2*)(outp + t * 2) = o;
}

// ---------------------------------------------------------------- q/k/v/g projections
__global__ __launch_bounds__(256) void proj_kernel(
    const float* __restrict__ qx, const float* __restrict__ kx,
    const float* __restrict__ Wq, const float* __restrict__ Wk,
    const float* __restrict__ Wv, const float* __restrict__ Wg,
    const float* __restrict__ bg,
    float* __restrict__ qs, float* __restrict__ ks,
    float* __restrict__ vs, float* __restrict__ gs)
{
    const int mat = blockIdx.y;
    const int r0 = blockIdx.x * 8;
    const float* x = (mat == 1 || mat == 2) ? kx : qx;
    const float* W = (mat == 0) ? Wq : (mat == 1) ? Wk : (mat == 2) ? Wv : Wg;
    float* outp    = (mat == 0) ? qs : (mat == 1) ? ks : (mat == 2) ? vs : gs;
    const int col = threadIdx.x;

    float acc[8] = {0.f,0.f,0.f,0.f,0.f,0.f,0.f,0.f};
    for (int cc = 0; cc < CN; cc += 4) {
        float w0 = W[(size_t)(cc + 0) * HC + col];
        float w1 = W[(size_t)(cc + 1) * HC + col];
        float w2 = W[(size_t)(cc + 2) * HC + col];
        float w3 = W[(size_t)(cc + 3) * HC + col];
#pragma unroll
        for (int r = 0; r < 8; ++r) {
            fx4 xv = *(const fx4*)(x + (size_t)(r0 + r) * CN + cc);
            acc[r] = fmaf(xv[0], w0, acc[r]);
            acc[r] = fmaf(xv[1], w1, acc[r]);
            acc[r] = fmaf(xv[2], w2, acc[r]);
            acc[r] = fmaf(xv[3], w3, acc[r]);
        }
    }
#pragma unroll
    for (int r = 0; r < 8; ++r) {
        float v = acc[r];
        if (mat == 0) v *= 0.17677669529663687f;   // C_HID^-0.5
        if (mat == 3) v = 1.f / (1.f + __expf(-(v + bg[col])));
        outp[(size_t)(r0 + r) * HC + col] = v;
    }
}

// ---------------------------------------------------------------- pair bias
// bias layout now [H][NI][NJ] for coalesced attention reads.
__global__ __launch_bounds__(256) void pair_bias_kernel(
    const float* __restrict__ pair, const float* __restrict__ pmask,
    const unsigned short* __restrict__ wcat, const float* __restrict__ scal,
    float* __restrict__ bias)
{
    const int lane = threadIdx.x & 63;
    const int wave = threadIdx.x >> 6;
    const int tile = blockIdx.x * 4 + wave;
    const int i  = tile / (NJ / 16);
    const int jt = (tile % (NJ / 16)) * 16;
    const int o  = lane & 15;
    const int kq = lane >> 4;

    bv8 bfrag[4];
#pragma unroll
    for (int s = 0; s < 4; ++s)
#pragma unroll
        for (int j = 0; j < 8; ++j)
            bfrag[s][j] = (short)wcat[(s * 32 + kq * 8 + j) * 16 + o];

    const float spb = scal[o];
    const float cpb = scal[16 + o];

    const float* prow = pair + ((size_t)i * NJ + (jt + o)) * CP + kq * 8;
    fx4 x0[4], x1[4];
#pragma unroll
    for (int s = 0; s < 4; ++s) {
        x0[s] = *(const fx4*)(prow + s * 32);
        x1[s] = *(const fx4*)(prow + s * 32 + 4);
    }
    float sum = 0.f, ssq = 0.f;
    bv8 afrag[4];
#pragma unroll
    for (int s = 0; s < 4; ++s) {
#pragma unroll
        for (int u = 0; u < 4; ++u) {
            float a = x0[s][u], b = x1[s][u];
            sum += a + b;
            ssq = fmaf(a, a, ssq);
            ssq = fmaf(b, b, ssq);
            afrag[s][u]     = f2bf(a);
            afrag[s][u + 4] = f2bf(b);
        }
    }
    sum += __shfl_xor(sum, 16); ssq += __shfl_xor(ssq, 16);
    sum += __shfl_xor(sum, 32); ssq += __shfl_xor(ssq, 32);

    fx4 acc = {0.f, 0.f, 0.f, 0.f};
#pragma unroll
    for (int s = 0; s < 4; ++s)
        acc = __builtin_amdgcn_mfma_f32_16x16x32_bf16(afrag[s], bfrag[s], acc, 0, 0, 0);

#pragma unroll
    for (int r = 0; r < 4; ++r) {
        const int p = kq * 4 + r;
        float sp = __shfl(sum, p);
        float qp = __shfl(ssq, p);
        float mean = sp * (1.f / CP);
        float var  = qp * (1.f / CP) - mean * mean;
        float rstd = rsqrtf(var + 1e-5f);
        float pre  = rstd * (acc[r] - mean * spb) + cpb;
        float part = __shfl_xor(pre, 8);
        if (o < 8) {
            float sig = 1.f / (1.f + __expf(-part));
            int j = jt + p;
            float b = pre * sig + (pmask[(size_t)i * NJ + j] - 1.f) * 1.0e9f;
            bias[((size_t)o * NI + i) * NJ + j] = b;
        }
    }
}

// ---------------------------------------------------------------- attention (MFMA)
// block = (head h, 32-row i-tile), 4 waves.
// Phase 1: each wave computes scores for a 192-wide j strip, exp (no max-sub:
//   scores are O(10) with LN'd inputs; masked -> exp(-1e9)=0), P->LDS bf16,
//   per-row partial sums. Phase 2: wave w owns output quadrant (it=w&1,
//   ct=w>>1), PV over all 768 j via MFMA from LDS P.
__global__ __launch_bounds__(256) void attn_kernel(
    const float* __restrict__ qs, const float* __restrict__ ks,
    const float* __restrict__ vs, const float* __restrict__ bias,
    const float* __restrict__ gs, float* __restrict__ og)
{
    __shared__ unsigned short P[32][776];   // stride 776: 16B-aligned rows
    __shared__ float sumbuf[4][32];
    const int i0 = blockIdx.x * 32;
    const int h  = blockIdx.y;
    const int t = threadIdx.x;
    const int w = t >> 6;
    const int lane = t & 63;
    const int rowl = lane & 15;
    const int g = lane >> 4;

    // Q fragments (rows i0+it*16+rowl, k = g*8+u)
    bv8 aq[2];
#pragma unroll
    for (int it = 0; it < 2; ++it) {
        const float* qp = qs + (size_t)(i0 + it * 16 + rowl) * HC + h * CH + g * 8;
        fx4 q0 = *(const fx4*)qp, q1 = *(const fx4*)(qp + 4);
#pragma unroll
        for (int u = 0; u < 4; ++u) { aq[it][u] = f2bf(q0[u]); aq[it][u + 4] = f2bf(q1[u]); }
    }

    float rs[2][4] = {{0.f,0.f,0.f,0.f},{0.f,0.f,0.f,0.f}};
    for (int jt = 0; jt < 12; ++jt) {
        const int jb = w * 192 + jt * 16;
        const float* kp = ks + (size_t)(jb + rowl) * HC + h * CH + g * 8;
        fx4 k0 = *(const fx4*)kp, k1 = *(const fx4*)(kp + 4);
        bv8 bk;
#pragma unroll
        for (int u = 0; u < 4; ++u) { bk[u] = f2bf(k0[u]); bk[u + 4] = f2bf(k1[u]); }
#pragma unroll
        for (int it = 0; it < 2; ++it) {
            fx4 acc = {0.f, 0.f, 0.f, 0.f};
            acc = __builtin_amdgcn_mfma_f32_16x16x32_bf16(aq[it], bk, acc, 0, 0, 0);
#pragma unroll
            for (int r = 0; r < 4; ++r) {
                const int il = it * 16 + g * 4 + r;
                float s = acc[r] + bias[((size_t)h * NI + (i0 + il)) * NJ + jb + rowl];
                float p = __expf(s);
                rs[it][r] += p;
                P[il][jb + rowl] = (unsigned short)f2bf(p);
            }
        }
    }
    // reduce partial sums over the 16 j-cols held across lanes&15
#pragma unroll
    for (int it = 0; it < 2; ++it)
#pragma unroll
        for (int r = 0; r < 4; ++r) {
            float v = rs[it][r];
            v += __shfl_xor(v, 1); v += __shfl_xor(v, 2);
            v += __shfl_xor(v, 4); v += __shfl_xor(v, 8);
            rs[it][r] = v;
        }
    if (rowl == 0) {
#pragma unroll
        for (int it = 0; it < 2; ++it)
#pragma unroll
            for (int r = 0; r < 4; ++r)
                sumbuf[w][it * 16 + g * 4 + r] = rs[it][r];
    }
    __syncthreads();

    // Phase 2: O quadrant (it, ct) over all j
    const int it = w & 1, ct = w >> 1;
    fx4 acc = {0.f, 0.f, 0.f, 0.f};
    for (int kk = 0; kk < 24; ++kk) {
        const int jb = kk * 32;
        bv8 ap = *(const bv8*)&P[it * 16 + rowl][jb + g * 8];
        bv8 bv;
#pragma unroll
        for (int u = 0; u < 8; ++u)
            bv[u] = f2bf(vs[(size_t)(jb + g * 8 + u) * HC + h * CH + ct * 16 + rowl]);
        acc = __builtin_amdgcn_mfma_f32_16x16x32_bf16(ap, bv, acc, 0, 0, 0);
    }
#pragma unroll
    for (int r = 0; r < 4; ++r) {
        const int il = it * 16 + g * 4 + r;
        float s = sumbuf[0][il] + sumbuf[1][il] + sumbuf[2][il] + sumbuf[3][il];
        size_t idx = (size_t)(i0 + il) * HC + h * CH + ct * 16 + rowl;
        og[idx] = acc[r] / s * gs[idx];
    }
}

// ---------------------------------------------------------------- output projection + residual
__global__ __launch_bounds__(256) void out_proj_kernel(
    const float* __restrict__ og, const float* __restrict__ qx,
    const float* __restrict__ Wo, const float* __restrict__ bo,
    const float* __restrict__ mi, float* __restrict__ outp)
{
    const int r0 = blockIdx.x * 4;
    const int t = threadIdx.x;
    float acc[4][2] = {{0,0},{0,0},{0,0},{0,0}};
    for (int cc = 0; cc < HC; cc += 4) {
        fx4 xr0 = *(const fx4*)(og + (size_t)(r0 + 0) * HC + cc);
        fx4 xr1 = *(const fx4*)(og + (size_t)(r0 + 1) * HC + cc);
        fx4 xr2 = *(const fx4*)(og + (size_t)(r0 + 2) * HC + cc);
        fx4 xr3 = *(const fx4*)(og + (size_t)(r0 + 3) * HC + cc);
#pragma unroll
        for (int u = 0; u < 4; ++u) {
            float w0 = Wo[(size_t)(cc + u) * CN + t];
            float w1 = Wo[(size_t)(cc + u) * CN + 256 + t];
            acc[0][0] = fmaf(xr0[u], w0, acc[0][0]); acc[0][1] = fmaf(xr0[u], w1, acc[0][1]);
            acc[1][0] = fmaf(xr1[u], w0, acc[1][0]); acc[1][1] = fmaf(xr1[u], w1, acc[1][1]);
            acc[2][0] = fmaf(xr2[u], w0, acc[2][0]); acc[2][1] = fmaf(xr2[u], w1, acc[2][1]);
            acc[3][0] = fmaf(xr3[u], w0, acc[3][0]); acc[3][1] = fmaf(xr3[u], w1, acc[3][1]);
        }
    }
#pragma unroll
    for (int r = 0; r < 4; ++r) {
        float mk = mi[r0 + r];
        size_t base = (size_t)(r0 + r) * CN;
        outp[base + t]       = qx[base + t]       + (acc[r][0] + bo[t])       * mk;
        outp[base + 256 + t] = qx[base + 256 + t] + (acc[r][1] + bo[t + 256]) * mk;
    }
}

// ---------------------------------------------------------------- launch
extern "C" void kernel_launch(void* const* d_in, const int* in_sizes, int n_in,
                              void* d_out, int out_size, void* d_ws, size_t ws_size,
                              hipStream_t stream)
{
    const float* node_i = (const float*)d_in[0];
    const float* node_j = (const float*)d_in[1];
    const float* pair   = (const float*)d_in[2];
    const float* pmask  = (const float*)d_in[3];
    const float* nmask  = (const float*)d_in[4];
    const float* ln_i_w = (const float*)d_in[5];
    const float* ln_i_b = (const float*)d_in[6];
    const float* ln_j_w = (const float*)d_in[7];
    const float* ln_j_b = (const float*)d_in[8];
    const float* ln_p_w = (const float*)d_in[9];
    const float* ln_p_b = (const float*)d_in[10];
    const float* W_pb   = (const float*)d_in[11];
    const float* b_pb   = (const float*)d_in[12];
    const float* W_pg   = (const float*)d_in[13];
    const float* b_pg   = (const float*)d_in[14];
    const float* Wq     = (const float*)d_in[15];
    const float* Wk     = (const float*)d_in[16];
    const float* Wv     = (const float*)d_in[17];
    const float* Wg     = (const float*)d_in[18];
    const float* bg     = (const float*)d_in[19];
    const float* Wo     = (const float*)d_in[20];
    const float* bo     = (const float*)d_in[21];
    float* outp = (float*)d_out;

    float* w  = (float*)d_ws;
    float* qx = w;                       // [NI][CN]
    float* kx = qx + (size_t)NI * CN;    // [NJ][CN]
    float* qs = kx + (size_t)NJ * CN;    // [NI][HC]
    float* ks = qs + (size_t)NI * HC;    // [NJ][HC]
    float* vs = ks + (size_t)NJ * HC;    // [NJ][HC]
    float* gs = vs + (size_t)NJ * HC;    // [NI][HC]
    float* og = gs + (size_t)NI * HC;    // [NI][HC]
    float* bias = og + (size_t)NI * HC;  // [NH][NI][NJ]
    unsigned short* wcat = (unsigned short*)(bias + (size_t)NI * NJ * NH);
    float* scal = (float*)(wcat + CP * 16);

    hipLaunchKernelGGL(prep_kernel, dim3(1), dim3(256), 0, stream,
                       ln_p_w, ln_p_b, W_pb, b_pb, W_pg, b_pg, wcat, scal);
    hipLaunchKernelGGL(ln_node_kernel, dim3(2 * NI), dim3(256), 0, stream,
                       node_i, node_j, ln_i_w, ln_i_b, ln_j_w, ln_j_b, qx, kx);
    hipLaunchKernelGGL(proj_kernel, dim3(NI / 8, 4), dim3(256), 0, stream,
                       qx, kx, Wq, Wk, Wv, Wg, bg, qs, ks, vs, gs);
    hipLaunchKernelGGL(pair_bias_kernel, dim3((NI * NJ) / 64), dim3(256), 0, stream,
                       pair, pmask, wcat, scal, bias);
    hipLaunchKernelGGL(attn_kernel, dim3(NI / 32, NH), dim3(256), 0, stream,
                       qs, ks, vs, bias, gs, og);
    hipLaunchKernelGGL(out_proj_kernel, dim3(NI / 4), dim3(256), 0, stream,
                       og, qx, Wo, bo, nmask, outp);
}

// Round 3
// 152.878 us; speedup vs baseline: 1.4035x; 1.1140x over previous
//
#include <hip/hip_runtime.h>
#include <hip/hip_bf16.h>

#define NI 768
#define NJ 768
#define CN 512
#define CP 128
#define NH 8
#define CH 32
#define HC 256   // NH*CH

typedef float  fx4  __attribute__((ext_vector_type(4)));
typedef float  fx2  __attribute__((ext_vector_type(2)));
typedef short  bv8  __attribute__((ext_vector_type(8)));

__device__ __forceinline__ short f2bf(float f) {
    __hip_bfloat16 h = __float2bfloat16(f);
    return *reinterpret_cast<short*>(&h);
}
__device__ __forceinline__ float bf2f(unsigned short u) {
    union { unsigned int u; float f; } c; c.u = ((unsigned int)u) << 16; return c.f;
}

// ---------------------------------------------------------------- prep
__global__ __launch_bounds__(256) void prep_kernel(
    const float* __restrict__ lnpw, const float* __restrict__ lnpb,
    const float* __restrict__ Wpb, const float* __restrict__ bpb,
    const float* __restrict__ Wpg, const float* __restrict__ bpg,
    unsigned short* __restrict__ wcat, float* __restrict__ scal)
{
    const int t = threadIdx.x;
    for (int idx = t; idx < CP * 16; idx += 256) {
        int c = idx >> 4, o = idx & 15;
        float w = (o < 8) ? Wpb[c * 8 + o] : Wpg[c * 8 + (o - 8)];
        wcat[idx] = (unsigned short)f2bf(lnpw[c] * w);
    }
    __syncthreads();
    if (t < 16) {
        float s = 0.f, cacc = 0.f;
        for (int c = 0; c < CP; ++c) {
            s += bf2f(wcat[c * 16 + t]);
            float w = (t < 8) ? Wpb[c * 8 + t] : Wpg[c * 8 + (t - 8)];
            cacc += lnpb[c] * w;
        }
        scal[t] = s;
        scal[16 + t] = cacc + ((t < 8) ? bpb[t] : bpg[t - 8]);
    }
}

// ---------------------------------------------------------------- fused front
// blocks [0,96):   i-side node path: LN(node_i) -> qx, q (scaled), gate
// blocks [96,192): j-side node path: LN(node_j) -> k, v
// blocks [192,9408): pair-bias tiles (4 waves x 16 pairs each)
__global__ __launch_bounds__(256) void fused_front_kernel(
    const float* __restrict__ node_i, const float* __restrict__ node_j,
    const float* __restrict__ ln_i_w, const float* __restrict__ ln_i_b,
    const float* __restrict__ ln_j_w, const float* __restrict__ ln_j_b,
    const float* __restrict__ Wq, const float* __restrict__ Wk,
    const float* __restrict__ Wv, const float* __restrict__ Wg,
    const float* __restrict__ bg,
    const float* __restrict__ pair, const float* __restrict__ pmask,
    const unsigned short* __restrict__ wcat, const float* __restrict__ scal,
    float* __restrict__ qx, float* __restrict__ qs, float* __restrict__ ks,
    float* __restrict__ vs, float* __restrict__ gs, float* __restrict__ bias)
{
    const int bid = blockIdx.x;
    if (bid < 192) {
        __shared__ float xs[8][CN];      // 16 KB LN'd rows
        __shared__ float red[4][8][2];
        const bool isj = bid >= 96;
        const int r0 = (isj ? bid - 96 : bid) * 8;
        const float* xin = isj ? node_j : node_i;
        const float* lw = isj ? ln_j_w : ln_i_w;
        const float* lb = isj ? ln_j_b : ln_i_b;
        const int t = threadIdx.x;
        const int wv = t >> 6;

        fx2 vrow[8]; float s8[8], q8[8];
#pragma unroll
        for (int r = 0; r < 8; ++r) {
            vrow[r] = *(const fx2*)(xin + (size_t)(r0 + r) * CN + t * 2);
            s8[r] = vrow[r][0] + vrow[r][1];
            q8[r] = vrow[r][0] * vrow[r][0] + vrow[r][1] * vrow[r][1];
        }
#pragma unroll
        for (int d = 1; d < 64; d <<= 1)
#pragma unroll
            for (int r = 0; r < 8; ++r) {
                s8[r] += __shfl_xor(s8[r], d);
                q8[r] += __shfl_xor(q8[r], d);
            }
        if ((t & 63) == 0)
#pragma unroll
            for (int r = 0; r < 8; ++r) { red[wv][r][0] = s8[r]; red[wv][r][1] = q8[r]; }
        __syncthreads();
        fx2 lwv = *(const fx2*)(lw + t * 2), lbv = *(const fx2*)(lb + t * 2);
#pragma unroll
        for (int r = 0; r < 8; ++r) {
            float s = red[0][r][0] + red[1][r][0] + red[2][r][0] + red[3][r][0];
            float q = red[0][r][1] + red[1][r][1] + red[2][r][1] + red[3][r][1];
            float mean = s * (1.f / CN);
            float var = q * (1.f / CN) - mean * mean;
            float rs = rsqrtf(var + 1e-5f);
            fx2 o;
            o[0] = (vrow[r][0] - mean) * rs * lwv[0] + lbv[0];
            o[1] = (vrow[r][1] - mean) * rs * lwv[1] + lbv[1];
            xs[r][t * 2] = o[0]; xs[r][t * 2 + 1] = o[1];
            if (!isj) *(fx2*)(qx + (size_t)(r0 + r) * CN + t * 2) = o;
        }
        __syncthreads();

        for (int m = 0; m < 2; ++m) {
            const float* W = isj ? (m ? Wv : Wk) : (m ? Wg : Wq);
            float acc[8] = {0.f,0.f,0.f,0.f,0.f,0.f,0.f,0.f};
            for (int cc = 0; cc < CN; cc += 4) {
                fx4 xv[8];
#pragma unroll
                for (int r = 0; r < 8; ++r) xv[r] = *(const fx4*)&xs[r][cc];
#pragma unroll
                for (int u = 0; u < 4; ++u) {
                    float w = W[(size_t)(cc + u) * HC + t];
#pragma unroll
                    for (int r = 0; r < 8; ++r) acc[r] = fmaf(xv[r][u], w, acc[r]);
                }
            }
#pragma unroll
            for (int r = 0; r < 8; ++r) {
                size_t o = (size_t)(r0 + r) * HC + t;
                if (!isj) {
                    if (m == 0) qs[o] = acc[r] * 0.17677669529663687f;
                    else        gs[o] = 1.f / (1.f + __expf(-(acc[r] + bg[t])));
                } else {
                    if (m == 0) ks[o] = acc[r];
                    else        vs[o] = acc[r];
                }
            }
        }
        return;
    }

    // ---- pair path ----
    const int lane = threadIdx.x & 63;
    const int wave = threadIdx.x >> 6;
    const int tile = (bid - 192) * 4 + wave;
    const int i  = tile / (NJ / 16);
    const int jt = (tile % (NJ / 16)) * 16;
    const int o  = lane & 15;
    const int kq = lane >> 4;

    bv8 bfrag[4];
#pragma unroll
    for (int s = 0; s < 4; ++s)
#pragma unroll
        for (int j = 0; j < 8; ++j)
            bfrag[s][j] = (short)wcat[(s * 32 + kq * 8 + j) * 16 + o];

    const float spb = scal[o];
    const float cpb = scal[16 + o];

    const float* prow = pair + ((size_t)i * NJ + (jt + o)) * CP + kq * 8;
    fx4 x0[4], x1[4];
#pragma unroll
    for (int s = 0; s < 4; ++s) {
        x0[s] = *(const fx4*)(prow + s * 32);
        x1[s] = *(const fx4*)(prow + s * 32 + 4);
    }
    float sum = 0.f, ssq = 0.f;
    bv8 afrag[4];
#pragma unroll
    for (int s = 0; s < 4; ++s) {
#pragma unroll
        for (int u = 0; u < 4; ++u) {
            float a = x0[s][u], b = x1[s][u];
            sum += a + b;
            ssq = fmaf(a, a, ssq);
            ssq = fmaf(b, b, ssq);
            afrag[s][u]     = f2bf(a);
            afrag[s][u + 4] = f2bf(b);
        }
    }
    sum += __shfl_xor(sum, 16); ssq += __shfl_xor(ssq, 16);
    sum += __shfl_xor(sum, 32); ssq += __shfl_xor(ssq, 32);

    fx4 acc = {0.f, 0.f, 0.f, 0.f};
#pragma unroll
    for (int s = 0; s < 4; ++s)
        acc = __builtin_amdgcn_mfma_f32_16x16x32_bf16(afrag[s], bfrag[s], acc, 0, 0, 0);

#pragma unroll
    for (int r = 0; r < 4; ++r) {
        const int p = kq * 4 + r;
        float sp = __shfl(sum, p);
        float qp = __shfl(ssq, p);
        float mean = sp * (1.f / CP);
        float var  = qp * (1.f / CP) - mean * mean;
        float rstd = rsqrtf(var + 1e-5f);
        float pre  = rstd * (acc[r] - mean * spb) + cpb;
        float part = __shfl_xor(pre, 8);
        if (o < 8) {
            float sig = 1.f / (1.f + __expf(-part));
            int j = jt + p;
            float b = pre * sig + (pmask[(size_t)i * NJ + j] - 1.f) * 1.0e9f;
            bias[((size_t)o * NI + i) * NJ + j] = b;
        }
    }
}

// ---------------------------------------------------------------- attention (MFMA)
__global__ __launch_bounds__(256) void attn_kernel(
    const float* __restrict__ qs, const float* __restrict__ ks,
    const float* __restrict__ vs, const float* __restrict__ bias,
    const float* __restrict__ gs, float* __restrict__ og)
{
    __shared__ unsigned short P[32][776];
    __shared__ float sumbuf[4][32];
    const int i0 = blockIdx.x * 32;
    const int h  = blockIdx.y;
    const int t = threadIdx.x;
    const int w = t >> 6;
    const int lane = t & 63;
    const int rowl = lane & 15;
    const int g = lane >> 4;

    bv8 aq[2];
#pragma unroll
    for (int it = 0; it < 2; ++it) {
        const float* qp = qs + (size_t)(i0 + it * 16 + rowl) * HC + h * CH + g * 8;
        fx4 q0 = *(const fx4*)qp, q1 = *(const fx4*)(qp + 4);
#pragma unroll
        for (int u = 0; u < 4; ++u) { aq[it][u] = f2bf(q0[u]); aq[it][u + 4] = f2bf(q1[u]); }
    }

    float rs[2][4] = {{0.f,0.f,0.f,0.f},{0.f,0.f,0.f,0.f}};
    for (int jt = 0; jt < 12; ++jt) {
        const int jb = w * 192 + jt * 16;
        const float* kp = ks + (size_t)(jb + rowl) * HC + h * CH + g * 8;
        fx4 k0 = *(const fx4*)kp, k1 = *(const fx4*)(kp + 4);
        bv8 bk;
#pragma unroll
        for (int u = 0; u < 4; ++u) { bk[u] = f2bf(k0[u]); bk[u + 4] = f2bf(k1[u]); }
#pragma unroll
        for (int it = 0; it < 2; ++it) {
            fx4 acc = {0.f, 0.f, 0.f, 0.f};
            acc = __builtin_amdgcn_mfma_f32_16x16x32_bf16(aq[it], bk, acc, 0, 0, 0);
#pragma unroll
            for (int r = 0; r < 4; ++r) {
                const int il = it * 16 + g * 4 + r;
                float s = acc[r] + bias[((size_t)h * NI + (i0 + il)) * NJ + jb + rowl];
                float p = __expf(s);
                rs[it][r] += p;
                P[il][jb + rowl] = (unsigned short)f2bf(p);
            }
        }
    }
#pragma unroll
    for (int it = 0; it < 2; ++it)
#pragma unroll
        for (int r = 0; r < 4; ++r) {
            float v = rs[it][r];
            v += __shfl_xor(v, 1); v += __shfl_xor(v, 2);
            v += __shfl_xor(v, 4); v += __shfl_xor(v, 8);
            rs[it][r] = v;
        }
    if (rowl == 0) {
#pragma unroll
        for (int it = 0; it < 2; ++it)
#pragma unroll
            for (int r = 0; r < 4; ++r)
                sumbuf[w][it * 16 + g * 4 + r] = rs[it][r];
    }
    __syncthreads();

    const int it = w & 1, ct = w >> 1;
    fx4 acc = {0.f, 0.f, 0.f, 0.f};
    for (int kk = 0; kk < 24; ++kk) {
        const int jb = kk * 32;
        bv8 ap = *(const bv8*)&P[it * 16 + rowl][jb + g * 8];
        bv8 bv;
#pragma unroll
        for (int u = 0; u < 8; ++u)
            bv[u] = f2bf(vs[(size_t)(jb + g * 8 + u) * HC + h * CH + ct * 16 + rowl]);
        acc = __builtin_amdgcn_mfma_f32_16x16x32_bf16(ap, bv, acc, 0, 0, 0);
    }
#pragma unroll
    for (int r = 0; r < 4; ++r) {
        const int il = it * 16 + g * 4 + r;
        float s = sumbuf[0][il] + sumbuf[1][il] + sumbuf[2][il] + sumbuf[3][il];
        size_t idx = (size_t)(i0 + il) * HC + h * CH + ct * 16 + rowl;
        og[idx] = acc[r] / s * gs[idx];
    }
}

// ---------------------------------------------------------------- output projection + residual
__global__ __launch_bounds__(256) void out_proj_kernel(
    const float* __restrict__ og, const float* __restrict__ qx,
    const float* __restrict__ Wo, const float* __restrict__ bo,
    const float* __restrict__ mi, float* __restrict__ outp)
{
    const int r0 = blockIdx.x * 2;
    const int t = threadIdx.x;
    float acc[2][2] = {{0,0},{0,0}};
    for (int cc = 0; cc < HC; cc += 4) {
        fx4 xr0 = *(const fx4*)(og + (size_t)(r0 + 0) * HC + cc);
        fx4 xr1 = *(const fx4*)(og + (size_t)(r0 + 1) * HC + cc);
#pragma unroll
        for (int u = 0; u < 4; ++u) {
            float w0 = Wo[(size_t)(cc + u) * CN + t];
            float w1 = Wo[(size_t)(cc + u) * CN + 256 + t];
            acc[0][0] = fmaf(xr0[u], w0, acc[0][0]); acc[0][1] = fmaf(xr0[u], w1, acc[0][1]);
            acc[1][0] = fmaf(xr1[u], w0, acc[1][0]); acc[1][1] = fmaf(xr1[u], w1, acc[1][1]);
        }
    }
#pragma unroll
    for (int r = 0; r < 2; ++r) {
        float mk = mi[r0 + r];
        size_t base = (size_t)(r0 + r) * CN;
        outp[base + t]       = qx[base + t]       + (acc[r][0] + bo[t])       * mk;
        outp[base + 256 + t] = qx[base + 256 + t] + (acc[r][1] + bo[t + 256]) * mk;
    }
}

// ---------------------------------------------------------------- launch
extern "C" void kernel_launch(void* const* d_in, const int* in_sizes, int n_in,
                              void* d_out, int out_size, void* d_ws, size_t ws_size,
                              hipStream_t stream)
{
    const float* node_i = (const float*)d_in[0];
    const float* node_j = (const float*)d_in[1];
    const float* pair   = (const float*)d_in[2];
    const float* pmask  = (const float*)d_in[3];
    const float* nmask  = (const float*)d_in[4];
    const float* ln_i_w = (const float*)d_in[5];
    const float* ln_i_b = (const float*)d_in[6];
    const float* ln_j_w = (const float*)d_in[7];
    const float* ln_j_b = (const float*)d_in[8];
    const float* ln_p_w = (const float*)d_in[9];
    const float* ln_p_b = (const float*)d_in[10];
    const float* W_pb   = (const float*)d_in[11];
    const float* b_pb   = (const float*)d_in[12];
    const float* W_pg   = (const float*)d_in[13];
    const float* b_pg   = (const float*)d_in[14];
    const float* Wq     = (const float*)d_in[15];
    const float* Wk     = (const float*)d_in[16];
    const float* Wv     = (const float*)d_in[17];
    const float* Wg     = (const float*)d_in[18];
    const float* bg     = (const float*)d_in[19];
    const float* Wo     = (const float*)d_in[20];
    const float* bo     = (const float*)d_in[21];
    float* outp = (float*)d_out;

    float* w  = (float*)d_ws;
    float* qx = w;                       // [NI][CN]
    float* qs = qx + (size_t)NI * CN;    // [NI][HC]
    float* ks = qs + (size_t)NI * HC;    // [NJ][HC]
    float* vs = ks + (size_t)NJ * HC;    // [NJ][HC]
    float* gs = vs + (size_t)NJ * HC;    // [NI][HC]
    float* og = gs + (size_t)NI * HC;    // [NI][HC]
    float* bias = og + (size_t)NI * HC;  // [NH][NI][NJ]
    unsigned short* wcat = (unsigned short*)(bias + (size_t)NI * NJ * NH);
    float* scal = (float*)(wcat + CP * 16);

    hipLaunchKernelGGL(prep_kernel, dim3(1), dim3(256), 0, stream,
                       ln_p_w, ln_p_b, W_pb, b_pb, W_pg, b_pg, wcat, scal);
    hipLaunchKernelGGL(fused_front_kernel, dim3(192 + (NI * NJ) / 64), dim3(256), 0, stream,
                       node_i, node_j, ln_i_w, ln_i_b, ln_j_w, ln_j_b,
                       Wq, Wk, Wv, Wg, bg, pair, pmask, wcat, scal,
                       qx, qs, ks, vs, gs, bias);
    hipLaunchKernelGGL(attn_kernel, dim3(NI / 32, NH), dim3(256), 0, stream,
                       qs, ks, vs, bias, gs, og);
    hipLaunchKernelGGL(out_proj_kernel, dim3(NI / 2), dim3(256), 0, stream,
                       og, qx, Wo, bo, nmask, outp);
}

// Round 4
// 111.983 us; speedup vs baseline: 1.9160x; 1.3652x over previous
//
#include <hip/hip_runtime.h>
#include <hip/hip_bf16.h>

#define NI 768
#define NJ 768
#define CN 512
#define CP 128
#define NH 8
#define CH 32
#define HC 256   // NH*CH

typedef float  fx4  __attribute__((ext_vector_type(4)));
typedef float  fx2  __attribute__((ext_vector_type(2)));
typedef short  bv8  __attribute__((ext_vector_type(8)));

__device__ __forceinline__ short f2bf(float f) {
    __hip_bfloat16 h = __float2bfloat16(f);
    return *reinterpret_cast<short*>(&h);
}
__device__ __forceinline__ float bf2f(unsigned short u) {
    union { unsigned int u; float f; } c; c.u = ((unsigned int)u) << 16; return c.f;
}

// ---------------------------------------------------------------- fused front
// blocks [0,96):   i-side: LN(node_i) -> qx(f32), qsb(bf16, scaled), gs(f32)
// blocks [96,192): j-side: LN(node_j) -> ksb(bf16), vtb(bf16 transposed [HC][NJ])
// blocks [192,9408): pair-bias tiles; folded weights rebuilt per-block in LDS
__global__ __launch_bounds__(256) void fused_front_kernel(
    const float* __restrict__ node_i, const float* __restrict__ node_j,
    const float* __restrict__ ln_i_w, const float* __restrict__ ln_i_b,
    const float* __restrict__ ln_j_w, const float* __restrict__ ln_j_b,
    const float* __restrict__ Wq, const float* __restrict__ Wk,
    const float* __restrict__ Wv, const float* __restrict__ Wg,
    const float* __restrict__ bg,
    const float* __restrict__ lnpw, const float* __restrict__ lnpb,
    const float* __restrict__ Wpb, const float* __restrict__ bpb,
    const float* __restrict__ Wpg, const float* __restrict__ bpg,
    const float* __restrict__ pair, const float* __restrict__ pmask,
    float* __restrict__ qx, unsigned short* __restrict__ qsb,
    unsigned short* __restrict__ ksb, unsigned short* __restrict__ vtb,
    float* __restrict__ gs, float* __restrict__ bias)
{
    const int bid = blockIdx.x;
    const int t = threadIdx.x;
    if (bid < 192) {
        __shared__ float xs[8][CN];      // 16 KB LN'd rows
        __shared__ float red[4][8][2];
        const bool isj = bid >= 96;
        const int r0 = (isj ? bid - 96 : bid) * 8;
        const float* xin = isj ? node_j : node_i;
        const float* lw = isj ? ln_j_w : ln_i_w;
        const float* lb = isj ? ln_j_b : ln_i_b;
        const int wv = t >> 6;

        fx2 vrow[8]; float s8[8], q8[8];
#pragma unroll
        for (int r = 0; r < 8; ++r) {
            vrow[r] = *(const fx2*)(xin + (size_t)(r0 + r) * CN + t * 2);
            s8[r] = vrow[r][0] + vrow[r][1];
            q8[r] = vrow[r][0] * vrow[r][0] + vrow[r][1] * vrow[r][1];
        }
#pragma unroll
        for (int d = 1; d < 64; d <<= 1)
#pragma unroll
            for (int r = 0; r < 8; ++r) {
                s8[r] += __shfl_xor(s8[r], d);
                q8[r] += __shfl_xor(q8[r], d);
            }
        if ((t & 63) == 0)
#pragma unroll
            for (int r = 0; r < 8; ++r) { red[wv][r][0] = s8[r]; red[wv][r][1] = q8[r]; }
        __syncthreads();
        fx2 lwv = *(const fx2*)(lw + t * 2), lbv = *(const fx2*)(lb + t * 2);
#pragma unroll
        for (int r = 0; r < 8; ++r) {
            float s = red[0][r][0] + red[1][r][0] + red[2][r][0] + red[3][r][0];
            float q = red[0][r][1] + red[1][r][1] + red[2][r][1] + red[3][r][1];
            float mean = s * (1.f / CN);
            float var = q * (1.f / CN) - mean * mean;
            float rs = rsqrtf(var + 1e-5f);
            fx2 o;
            o[0] = (vrow[r][0] - mean) * rs * lwv[0] + lbv[0];
            o[1] = (vrow[r][1] - mean) * rs * lwv[1] + lbv[1];
            xs[r][t * 2] = o[0]; xs[r][t * 2 + 1] = o[1];
            if (!isj) *(fx2*)(qx + (size_t)(r0 + r) * CN + t * 2) = o;
        }
        __syncthreads();

        for (int m = 0; m < 2; ++m) {
            const float* W = isj ? (m ? Wv : Wk) : (m ? Wg : Wq);
            float acc[8] = {0.f,0.f,0.f,0.f,0.f,0.f,0.f,0.f};
            for (int cc = 0; cc < CN; cc += 4) {
                fx4 xv[8];
#pragma unroll
                for (int r = 0; r < 8; ++r) xv[r] = *(const fx4*)&xs[r][cc];
#pragma unroll
                for (int u = 0; u < 4; ++u) {
                    float w = W[(size_t)(cc + u) * HC + t];
#pragma unroll
                    for (int r = 0; r < 8; ++r) acc[r] = fmaf(xv[r][u], w, acc[r]);
                }
            }
            if (!isj) {
                if (m == 0) {
#pragma unroll
                    for (int r = 0; r < 8; ++r)
                        qsb[(size_t)(r0 + r) * HC + t] =
                            (unsigned short)f2bf(acc[r] * 0.17677669529663687f);
                } else {
#pragma unroll
                    for (int r = 0; r < 8; ++r)
                        gs[(size_t)(r0 + r) * HC + t] =
                            1.f / (1.f + __expf(-(acc[r] + bg[t])));
                }
            } else {
                if (m == 0) {
#pragma unroll
                    for (int r = 0; r < 8; ++r)
                        ksb[(size_t)(r0 + r) * HC + t] = (unsigned short)f2bf(acc[r]);
                } else {
                    bv8 vv;
#pragma unroll
                    for (int r = 0; r < 8; ++r) vv[r] = f2bf(acc[r]);
                    *(bv8*)&vtb[(size_t)t * NJ + r0] = vv;   // transposed [HC][NJ]
                }
            }
        }
        return;
    }

    // ---- pair path ----
    __shared__ unsigned short wcatT[16][136];   // [o][c], padded stride
    __shared__ float redS[16][16], redC[16][16];
    __shared__ float scalS[16], scalC[16];
    {
        const int o = t & 15, cg = t >> 4;      // 16 col-groups of 8 channels
        float pS = 0.f, pC = 0.f;
#pragma unroll
        for (int e = 0; e < 8; ++e) {
            int c = cg * 8 + e;
            float w = (o < 8) ? Wpb[c * 8 + o] : Wpg[c * 8 + (o - 8)];
            float wv = lnpw[c] * w;
            short b = f2bf(wv);
            wcatT[o][c] = (unsigned short)b;
            pS += bf2f((unsigned short)b);
            pC += lnpb[c] * w;
        }
        redS[cg][o] = pS; redC[cg][o] = pC;
        __syncthreads();
        if (t < 16) {
            float s = 0.f, c2 = 0.f;
#pragma unroll
            for (int k = 0; k < 16; ++k) { s += redS[k][t]; c2 += redC[k][t]; }
            scalS[t] = s;
            scalC[t] = c2 + ((t < 8) ? bpb[t] : bpg[t - 8]);
        }
        __syncthreads();
    }

    const int lane = t & 63;
    const int wave = t >> 6;
    const int tile = (bid - 192) * 4 + wave;
    const int i  = tile / (NJ / 16);
    const int jt = (tile % (NJ / 16)) * 16;
    const int o  = lane & 15;
    const int kq = lane >> 4;

    bv8 bfrag[4];
#pragma unroll
    for (int s = 0; s < 4; ++s)
        bfrag[s] = *(const bv8*)&wcatT[o][s * 32 + kq * 8];

    const float spb = scalS[o];
    const float cpb = scalC[o];

    const float* prow = pair + ((size_t)i * NJ + (jt + o)) * CP + kq * 8;
    fx4 x0[4], x1[4];
#pragma unroll
    for (int s = 0; s < 4; ++s) {
        x0[s] = *(const fx4*)(prow + s * 32);
        x1[s] = *(const fx4*)(prow + s * 32 + 4);
    }
    float sum = 0.f, ssq = 0.f;
    bv8 afrag[4];
#pragma unroll
    for (int s = 0; s < 4; ++s) {
#pragma unroll
        for (int u = 0; u < 4; ++u) {
            float a = x0[s][u], b = x1[s][u];
            sum += a + b;
            ssq = fmaf(a, a, ssq);
            ssq = fmaf(b, b, ssq);
            afrag[s][u]     = f2bf(a);
            afrag[s][u + 4] = f2bf(b);
        }
    }
    sum += __shfl_xor(sum, 16); ssq += __shfl_xor(ssq, 16);
    sum += __shfl_xor(sum, 32); ssq += __shfl_xor(ssq, 32);

    fx4 acc = {0.f, 0.f, 0.f, 0.f};
#pragma unroll
    for (int s = 0; s < 4; ++s)
        acc = __builtin_amdgcn_mfma_f32_16x16x32_bf16(afrag[s], bfrag[s], acc, 0, 0, 0);

#pragma unroll
    for (int r = 0; r < 4; ++r) {
        const int p = kq * 4 + r;
        float sp = __shfl(sum, p);
        float qp = __shfl(ssq, p);
        float mean = sp * (1.f / CP);
        float var  = qp * (1.f / CP) - mean * mean;
        float rstd = rsqrtf(var + 1e-5f);
        float pre  = rstd * (acc[r] - mean * spb) + cpb;
        float part = __shfl_xor(pre, 8);
        if (o < 8) {
            float sig = 1.f / (1.f + __expf(-part));
            int j = jt + p;
            float b = pre * sig + (pmask[(size_t)i * NJ + j] - 1.f) * 1.0e9f;
            bias[((size_t)o * NI + i) * NJ + j] = b;
        }
    }
}

// ---------------------------------------------------------------- attention (MFMA, j-split)
// grid (24, 8, 2): (32-row i-tile, head, j-half of 384). Writes partial
// num[32][32] and den[32] per block; combined downstream (deterministic).
__global__ __launch_bounds__(256) void attn_kernel(
    const short* __restrict__ qsb, const short* __restrict__ ksb,
    const short* __restrict__ vtb, const float* __restrict__ bias,
    float* __restrict__ pnum, float* __restrict__ pden)
{
    __shared__ unsigned short P[32][392];   // 384 + 8 pad
    __shared__ float sumbuf[4][32];
    const int i0 = blockIdx.x * 32;
    const int h  = blockIdx.y;
    const int jh = blockIdx.z;
    const int jbase = jh * 384;
    const int pb = ((int)blockIdx.x * NH + h) * 2 + jh;
    const int t = threadIdx.x;
    const int w = t >> 6;
    const int lane = t & 63;
    const int rowl = lane & 15;
    const int g = lane >> 4;

    bv8 aq[2];
#pragma unroll
    for (int it = 0; it < 2; ++it)
        aq[it] = *(const bv8*)&qsb[(size_t)(i0 + it * 16 + rowl) * HC + h * CH + g * 8];

    float rs[2][4] = {{0.f,0.f,0.f,0.f},{0.f,0.f,0.f,0.f}};
    for (int jt = 0; jt < 6; ++jt) {
        const int jloc = w * 96 + jt * 16;
        const int jb = jbase + jloc;
        bv8 bk = *(const bv8*)&ksb[(size_t)(jb + rowl) * HC + h * CH + g * 8];
#pragma unroll
        for (int it = 0; it < 2; ++it) {
            fx4 acc = {0.f, 0.f, 0.f, 0.f};
            acc = __builtin_amdgcn_mfma_f32_16x16x32_bf16(aq[it], bk, acc, 0, 0, 0);
#pragma unroll
            for (int r = 0; r < 4; ++r) {
                const int il = it * 16 + g * 4 + r;
                float s = acc[r] + bias[((size_t)h * NI + (i0 + il)) * NJ + jb + rowl];
                float p = __expf(s);
                rs[it][r] += p;
                P[il][jloc + rowl] = (unsigned short)f2bf(p);
            }
        }
    }
#pragma unroll
    for (int it = 0; it < 2; ++it)
#pragma unroll
        for (int r = 0; r < 4; ++r) {
            float v = rs[it][r];
            v += __shfl_xor(v, 1); v += __shfl_xor(v, 2);
            v += __shfl_xor(v, 4); v += __shfl_xor(v, 8);
            rs[it][r] = v;
        }
    if (rowl == 0) {
#pragma unroll
        for (int it = 0; it < 2; ++it)
#pragma unroll
            for (int r = 0; r < 4; ++r)
                sumbuf[w][it * 16 + g * 4 + r] = rs[it][r];
    }
    __syncthreads();

    if (t < 32)
        pden[(size_t)pb * 32 + t] =
            sumbuf[0][t] + sumbuf[1][t] + sumbuf[2][t] + sumbuf[3][t];

    const int it = w & 1, ct = w >> 1;
    fx4 acc = {0.f, 0.f, 0.f, 0.f};
    for (int kk = 0; kk < 12; ++kk) {
        const int jloc = kk * 32;
        bv8 ap = *(const bv8*)&P[it * 16 + rowl][jloc + g * 8];
        bv8 bv = *(const bv8*)&vtb[(size_t)(h * CH + ct * 16 + rowl) * NJ + jbase + jloc + g * 8];
        acc = __builtin_amdgcn_mfma_f32_16x16x32_bf16(ap, bv, acc, 0, 0, 0);
    }
#pragma unroll
    for (int r = 0; r < 4; ++r) {
        const int il = it * 16 + g * 4 + r;
        pnum[(size_t)pb * 1024 + il * 32 + ct * 16 + rowl] = acc[r];
    }
}

// ---------------------------------------------------------------- combine + output projection + residual
__global__ __launch_bounds__(256) void combine_out_kernel(
    const float* __restrict__ pnum, const float* __restrict__ pden,
    const float* __restrict__ gs, const float* __restrict__ qx,
    const float* __restrict__ Wo, const float* __restrict__ bo,
    const float* __restrict__ mi, float* __restrict__ outp)
{
    __shared__ float ogl[2][HC];
    const int r0 = blockIdx.x * 2;
    const int t = threadIdx.x;
    const int h = t >> 5, c = t & 31;
#pragma unroll
    for (int r = 0; r < 2; ++r) {
        const int i = r0 + r;
        const int pb = ((i >> 5) * NH + h) * 2;
        const int il = i & 31;
        float n = pnum[(size_t)(pb + 0) * 1024 + il * 32 + c]
                + pnum[(size_t)(pb + 1) * 1024 + il * 32 + c];
        float d = pden[(size_t)(pb + 0) * 32 + il]
                + pden[(size_t)(pb + 1) * 32 + il];
        ogl[r][t] = n / d * gs[(size_t)i * HC + t];
    }
    __syncthreads();

    float acc[2][2] = {{0,0},{0,0}};
    for (int cc = 0; cc < HC; cc += 4) {
        fx4 xr0 = *(const fx4*)&ogl[0][cc];
        fx4 xr1 = *(const fx4*)&ogl[1][cc];
#pragma unroll
        for (int u = 0; u < 4; ++u) {
            float w0 = Wo[(size_t)(cc + u) * CN + t];
            float w1 = Wo[(size_t)(cc + u) * CN + 256 + t];
            acc[0][0] = fmaf(xr0[u], w0, acc[0][0]); acc[0][1] = fmaf(xr0[u], w1, acc[0][1]);
            acc[1][0] = fmaf(xr1[u], w0, acc[1][0]); acc[1][1] = fmaf(xr1[u], w1, acc[1][1]);
        }
    }
#pragma unroll
    for (int r = 0; r < 2; ++r) {
        float mk = mi[r0 + r];
        size_t base = (size_t)(r0 + r) * CN;
        outp[base + t]       = qx[base + t]       + (acc[r][0] + bo[t])       * mk;
        outp[base + 256 + t] = qx[base + 256 + t] + (acc[r][1] + bo[t + 256]) * mk;
    }
}

// ---------------------------------------------------------------- launch
extern "C" void kernel_launch(void* const* d_in, const int* in_sizes, int n_in,
                              void* d_out, int out_size, void* d_ws, size_t ws_size,
                              hipStream_t stream)
{
    const float* node_i = (const float*)d_in[0];
    const float* node_j = (const float*)d_in[1];
    const float* pair   = (const float*)d_in[2];
    const float* pmask  = (const float*)d_in[3];
    const float* nmask  = (const float*)d_in[4];
    const float* ln_i_w = (const float*)d_in[5];
    const float* ln_i_b = (const float*)d_in[6];
    const float* ln_j_w = (const float*)d_in[7];
    const float* ln_j_b = (const float*)d_in[8];
    const float* ln_p_w = (const float*)d_in[9];
    const float* ln_p_b = (const float*)d_in[10];
    const float* W_pb   = (const float*)d_in[11];
    const float* b_pb   = (const float*)d_in[12];
    const float* W_pg   = (const float*)d_in[13];
    const float* b_pg   = (const float*)d_in[14];
    const float* Wq     = (const float*)d_in[15];
    const float* Wk     = (const float*)d_in[16];
    const float* Wv     = (const float*)d_in[17];
    const float* Wg     = (const float*)d_in[18];
    const float* bg     = (const float*)d_in[19];
    const float* Wo     = (const float*)d_in[20];
    const float* bo     = (const float*)d_in[21];
    float* outp = (float*)d_out;

    float* fw = (float*)d_ws;
    float* qx   = fw;                          // [NI][CN]
    float* gs   = qx + (size_t)NI * CN;        // [NI][HC]
    float* bias = gs + (size_t)NI * HC;        // [NH][NI][NJ]
    float* pnum = bias + (size_t)NH * NI * NJ; // [24*8*2][32][32]
    float* pden = pnum + (size_t)24 * NH * 2 * 1024; // [24*8*2][32]
    unsigned short* qsb = (unsigned short*)(pden + (size_t)24 * NH * 2 * 32); // [NI][HC]
    unsigned short* ksb = qsb + (size_t)NI * HC;   // [NJ][HC]
    unsigned short* vtb = ksb + (size_t)NJ * HC;   // [HC][NJ]

    hipLaunchKernelGGL(fused_front_kernel, dim3(192 + (NI * NJ) / 64), dim3(256), 0, stream,
                       node_i, node_j, ln_i_w, ln_i_b, ln_j_w, ln_j_b,
                       Wq, Wk, Wv, Wg, bg,
                       ln_p_w, ln_p_b, W_pb, b_pb, W_pg, b_pg,
                       pair, pmask,
                       qx, qsb, ksb, vtb, gs, bias);
    hipLaunchKernelGGL(attn_kernel, dim3(NI / 32, NH, 2), dim3(256), 0, stream,
                       (const short*)qsb, (const short*)ksb, (const short*)vtb,
                       bias, pnum, pden);
    hipLaunchKernelGGL(combine_out_kernel, dim3(NI / 2), dim3(256), 0, stream,
                       pnum, pden, gs, qx, Wo, bo, nmask, outp);
}